// Round 3
// baseline (495.882 us; speedup 1.0000x reference)
//
#include <hip/hip_runtime.h>
#include <hip/hip_cooperative_groups.h>

namespace cg = cooperative_groups;

// Max-unpooling (SegNet) scatter. B=32, H=W=64, C=128.
//   image_size = H*W*C        = 2^19  (per-batch pooled elements)
//   out_image  = 4*image_size = 2^21  (per-batch output elements)
// Output flat index = b*out_image + (am mod out_image).
//
// R3: fused zero+scatter into one cooperative kernel (grid.sync between
// phases). Removes one graph-node launch gap, uses grid-stride for both
// phases (rocclr-fill-style, 6.4 TB/s proven), and lets the scatter hit
// still-dirty zero lines in L2. Uniqueness of unpool targets => plain
// stores, no atomics (see R2 note).

#define IMAGE_SHIFT 19
#define OUTIMG_SHIFT 21
#define OUTIMG_MASK ((1 << OUTIMG_SHIFT) - 1)

__global__ __launch_bounds__(256) void unpool_fused(
    const float4* __restrict__ values,
    const int4*  __restrict__ argmax,
    float*       __restrict__ out,
    int out_n4,   // output float4 count (2^24)
    int n4)       // input  float4 count (2^22)
{
    const int tid      = blockIdx.x * blockDim.x + threadIdx.x;
    const int nthreads = gridDim.x * blockDim.x;

    // ---- Phase 1: zero the (poisoned) output, coalesced grid-stride ----
    float4* __restrict__ out4 = (float4*)out;
    const float4 z = make_float4(0.f, 0.f, 0.f, 0.f);
    for (int i = tid; i < out_n4; i += nthreads)
        out4[i] = z;

    cg::this_grid().sync();   // all zeros visible before any scatter store

    // ---- Phase 2: scatter values to decoded argmax positions ----
    for (int t = tid; t < n4; t += nthreads) {
        float4 v = values[t];
        int4   a = argmax[t];

        int base_elem = t << 2;
        int obase = (base_elem >> IMAGE_SHIFT) << OUTIMG_SHIFT;

        int ix = a.x & OUTIMG_MASK;
        int iy = a.y & OUTIMG_MASK;
        int iz = a.z & OUTIMG_MASK;
        int iw = a.w & OUTIMG_MASK;

        // Fast path: 4 contiguous 16B-aligned targets -> one float4 store
        // (always true when the 4 elements are consecutive channels of one
        // output position; degrades gracefully otherwise).
        if (((ix & 3) == 0) && iy == ix + 1 && iz == ix + 2 && iw == ix + 3) {
            *(float4*)(out + obase + ix) = v;
        } else {
            out[obase + ix] = v.x;
            out[obase + iy] = v.y;
            out[obase + iz] = v.z;
            out[obase + iw] = v.w;
        }
    }
}

extern "C" void kernel_launch(void* const* d_in, const int* in_sizes, int n_in,
                              void* d_out, int out_size, void* d_ws, size_t ws_size,
                              hipStream_t stream) {
    const float4* values = (const float4*)d_in[0];
    const int4*   argmax = (const int4*)d_in[1];
    float*        out    = (float*)d_out;

    int n4     = in_sizes[0] >> 2;   // 2^22 input groups
    int out_n4 = out_size    >> 2;   // 2^24 output groups

    // 1024 blocks = 4 blocks/CU on 256 CUs; 8 VGPR / 0 LDS kernel is
    // trivially co-resident (cooperative launch requirement).
    dim3 grid(1024), block(256);
    void* args[] = { (void*)&values, (void*)&argmax, (void*)&out,
                     (void*)&out_n4, (void*)&n4 };
    hipLaunchCooperativeKernel((const void*)unpool_fused, grid, block,
                               args, 0, stream);
}

// Round 4
// 349.298 us; speedup vs baseline: 1.4197x; 1.4197x over previous
//
#include <hip/hip_runtime.h>

// Max-unpooling (SegNet) scatter. B=32, H=W=64, C=128.
//   image_size = H*W*C        = 2^19  (per-batch pooled elements)
//   out_image  = 4*image_size = 2^21  (per-batch output elements)
// Output flat index = b*out_image + (am mod out_image).
//
// R4: revert R3's cooperative fusion (1024-block coop grid => only 1.78 TB/s,
// 232 us — write streaming on gfx950 needs a huge grid for MLP, not
// grid-stride loops). Back to R2's two-kernel structure (84 us combined,
// inferred), with zero_out widened to 2 float4 stores/thread.
// Uniqueness of unpool targets => plain stores, no atomics (see R2 note).

#define IMAGE_SHIFT 19
#define OUTIMG_SHIFT 21
#define OUTIMG_MASK ((1 << OUTIMG_SHIFT) - 1)

__global__ __launch_bounds__(256) void zero_out(float4* __restrict__ out, int n4)
{
    // 2 float4 stores per thread, consecutive addresses within the thread's
    // pair slot: lane i writes [2t, 2t+1] -> 32B per lane, fully coalesced.
    int t = blockIdx.x * blockDim.x + threadIdx.x;
    int i = t << 1;
    const float4 z = make_float4(0.f, 0.f, 0.f, 0.f);
    if (i < n4)     out[i]     = z;
    if (i + 1 < n4) out[i + 1] = z;
}

__global__ __launch_bounds__(256) void unpool_scatter(
    const float4* __restrict__ values,
    const int4*  __restrict__ argmax,
    float*       __restrict__ out,
    int n4)
{
    int t = blockIdx.x * blockDim.x + threadIdx.x;
    if (t >= n4) return;

    float4 v = values[t];
    int4   a = argmax[t];

    int base_elem = t << 2;
    int obase = (base_elem >> IMAGE_SHIFT) << OUTIMG_SHIFT;

    int ix = a.x & OUTIMG_MASK;
    int iy = a.y & OUTIMG_MASK;
    int iz = a.z & OUTIMG_MASK;
    int iw = a.w & OUTIMG_MASK;

    // Fast path: 4 contiguous 16B-aligned targets -> one float4 store
    // (true when the 4 elements are consecutive channels of one output
    // position; degrades gracefully otherwise).
    if (((ix & 3) == 0) && iy == ix + 1 && iz == ix + 2 && iw == ix + 3) {
        *(float4*)(out + obase + ix) = v;
    } else {
        out[obase + ix] = v.x;
        out[obase + iy] = v.y;
        out[obase + iz] = v.z;
        out[obase + iw] = v.w;
    }
}

extern "C" void kernel_launch(void* const* d_in, const int* in_sizes, int n_in,
                              void* d_out, int out_size, void* d_ws, size_t ws_size,
                              hipStream_t stream) {
    const float4* values = (const float4*)d_in[0];
    const int4*   argmax = (const int4*)d_in[1];
    float*        out    = (float*)d_out;

    int n4     = in_sizes[0] >> 2;   // 2^22 input groups
    int out_n4 = out_size    >> 2;   // 2^24 output groups

    const int block = 256;

    // Zero: 2 float4/thread -> out_n4/2 threads -> 32768 blocks.
    int zthreads = (out_n4 + 1) >> 1;
    zero_out<<<(zthreads + block - 1) / block, block, 0, stream>>>(
        (float4*)out, out_n4);

    unpool_scatter<<<(n4 + block - 1) / block, block, 0, stream>>>(
        values, argmax, (float*)out, n4);
}